// Round 6
// baseline (167.717 us; speedup 1.0000x reference)
//
#include <hip/hip_runtime.h>
#include <hip/hip_bf16.h>

#define IMG   512
#define TW    32
#define TH    32
#define WS    11
#define NP    96
#define NSLOT 256
#define HROWS 48
#define HCOLS 36

typedef __attribute__((ext_vector_type(8)))  short bfrag8;
typedef __attribute__((ext_vector_type(16))) float facc16;

#define GAUSS_W { \
    0.00102837990674f, 0.00759883148699f, 0.03600079242909f, \
    0.10936069869137f, 0.21300538108707f, 0.26601190869814f, \
    0.21300538108707f, 0.10936069869137f, 0.03600079242909f, \
    0.00759883148699f, 0.00102837990674f }

static __device__ __forceinline__ ushort f2bf(float x) {
    __hip_bfloat16 h = __float2bfloat16(x);
    return __builtin_bit_cast(ushort, h);
}

// Build the A-operand (Gaussian band matrix) fragments once: G[i][k] = W[k-i].
// A-fragment layout for mfma_f32_32x32x16_bf16: lane l holds A[l&31][8*(l>>5)+e].
// hi fragments at gw[0..1535], lo (split-weight residual) at gw[1536..3071].
__global__ void build_g(ushort* __restrict__ gw) {
    constexpr float W[WS] = GAUSS_W;
    const int lane = threadIdx.x;          // 64 threads
    const int row  = lane & 31;
    const int kg   = (lane >> 5) * 8;
    for (int s = 0; s < 3; ++s) {
        for (int e = 0; e < 8; ++e) {
            const int k = 16 * s + kg + e;
            const int d = k - row;
            float wv = 0.f;
            #pragma unroll
            for (int q = 0; q < WS; ++q) if (d == q) wv = W[q];
            const float hi = __bfloat162float(__float2bfloat16(wv));
            const float lo = wv - hi;
            gw[(s * 64 + lane) * 8 + e]        = f2bf(hi);
            gw[1536 + (s * 64 + lane) * 8 + e] = f2bf(lo);
        }
    }
}

__global__ __launch_bounds__(64) void ssim_main(const float* __restrict__ img1,
                                                const float* __restrict__ img2,
                                                const ushort* __restrict__ gw,
                                                double* __restrict__ acc) {
    constexpr float W[WS] = GAUSS_W;
    __shared__ ushort H[5][HROWS][HCOLS];   // 17,280 B, bf16 h-conv signals

    const int lane = threadIdx.x;
    const int bx = blockIdx.x, by = blockIdx.y;
    const float* p1 = img1 + (size_t)blockIdx.z * (IMG * IMG);
    const float* p2 = img2 + (size_t)blockIdx.z * (IMG * IMG);

    // zero K-pad rows 42..47 of each plane (garbage bits could be NaN; 0*NaN=NaN)
    #pragma unroll
    for (int s = 0; s < 5; ++s) {
        uint* zp = (uint*)&H[s][42][0];     // 6 rows * 36 u16 = 108 dwords
        for (int i = lane; i < 108; i += 64) zp[i] = 0;
    }

    // ---------- Phase 1: horizontal conv (f32 VALU), write bf16 to LDS ------
    for (int u = lane; u < 168; u += 64) {
        const int r  = u >> 2;          // padded row 0..41
        const int ch = u & 3;           // 8-wide col chunk
        const int gy = by * TH + r - 5;
        const bool rowOK = (unsigned)gy < IMG;
        const float* r1 = p1 + (size_t)gy * IMG;
        const float* r2 = p2 + (size_t)gy * IMG;

        float a1[8], a2[8], a11[8], a22[8], a12[8];
        #pragma unroll
        for (int o = 0; o < 8; ++o) { a1[o]=0.f; a2[o]=0.f; a11[o]=0.f; a22[o]=0.f; a12[o]=0.f; }

        #pragma unroll
        for (int j = 0; j < 6; ++j) {
            const int gx = bx * TW + ch * 8 - 8 + 4 * j;
            float4 A = make_float4(0.f,0.f,0.f,0.f), B = A;
            if (rowOK && (unsigned)gx < IMG) {
                A = *(const float4*)(r1 + gx);
                B = *(const float4*)(r2 + gx);
            }
            const float e1[4] = {A.x,A.y,A.z,A.w};
            const float e2[4] = {B.x,B.y,B.z,B.w};
            #pragma unroll
            for (int e = 0; e < 4; ++e) {
                const int i = 4*j + e;                 // taps live in 3..20
                if (i < 3 || i > 20) continue;
                const float x1 = e1[e], x2 = e2[e];
                const float q11 = x1*x1, q22 = x2*x2, q12 = x1*x2;
                #pragma unroll
                for (int o = 0; o < 8; ++o) {
                    const int t = i - 3 - o;
                    if (t >= 0 && t < WS) {
                        a1[o]  += W[t]*x1;  a2[o]  += W[t]*x2;
                        a11[o] += W[t]*q11; a22[o] += W[t]*q22; a12[o] += W[t]*q12;
                    }
                }
            }
        }

        #define WRSIG(S, ARR) \
            *(ushort4*)&H[S][r][ch*8]   = make_ushort4(f2bf(ARR[0]),f2bf(ARR[1]),f2bf(ARR[2]),f2bf(ARR[3])); \
            *(ushort4*)&H[S][r][ch*8+4] = make_ushort4(f2bf(ARR[4]),f2bf(ARR[5]),f2bf(ARR[6]),f2bf(ARR[7]));
        WRSIG(0, a1) WRSIG(1, a2) WRSIG(2, a11) WRSIG(3, a22) WRSIG(4, a12)
        #undef WRSIG
    }

    // A-operand fragments (band-matrix), L2-broadcast loads
    const bfrag8* gfrag = (const bfrag8*)gw;
    const bfrag8 ghi0 = gfrag[lane], ghi1 = gfrag[64 + lane], ghi2 = gfrag[128 + lane];
    const bfrag8 glo0 = gfrag[192 + lane], glo1 = gfrag[256 + lane], glo2 = gfrag[320 + lane];

    __syncthreads();

    // ---------- Phase 2: vertical conv via MFMA ----------------------------
    const int col = lane & 31;
    const int kg  = (lane >> 5) * 8;

    facc16 accs[5];
    #pragma unroll
    for (int s = 0; s < 5; ++s) {
        facc16 a = {};
        #define KSTEP(T, GHI, GLO) { \
            const int kb = 16*T + kg; \
            union { uint u[4]; bfrag8 v; } bb; \
            bb.u[0] = (uint)H[s][kb+0][col] | ((uint)H[s][kb+1][col] << 16); \
            bb.u[1] = (uint)H[s][kb+2][col] | ((uint)H[s][kb+3][col] << 16); \
            bb.u[2] = (uint)H[s][kb+4][col] | ((uint)H[s][kb+5][col] << 16); \
            bb.u[3] = (uint)H[s][kb+6][col] | ((uint)H[s][kb+7][col] << 16); \
            a = __builtin_amdgcn_mfma_f32_32x32x16_bf16(GHI, bb.v, a, 0, 0, 0); \
            a = __builtin_amdgcn_mfma_f32_32x32x16_bf16(GLO, bb.v, a, 0, 0, 0); }
        KSTEP(0, ghi0, glo0)
        KSTEP(1, ghi1, glo1)
        KSTEP(2, ghi2, glo2)
        #undef KSTEP
        accs[s] = a;
    }

    // ---------- Epilogue: SSIM per pixel (layout-invariant sum) ------------
    const float C1 = 0.01f*0.01f, C2 = 0.03f*0.03f;
    float lsum = 0.f;
    #pragma unroll
    for (int r = 0; r < 16; ++r) {
        const float mu1 = accs[0][r], mu2 = accs[1][r];
        const float m11 = accs[2][r], m22 = accs[3][r], m12 = accs[4][r];
        const float mu1s = mu1*mu1, mu2s = mu2*mu2, mu12 = mu1*mu2;
        const float s11 = m11 - mu1s;
        const float s22 = m22 - mu2s;
        const float s12 = m12 - mu12;
        const float num = (2.f*mu12 + C1) * (2.f*s12 + C2);
        const float den = (mu1s + mu2s + C1) * (s11 + s22 + C2);
        lsum += num * __builtin_amdgcn_rcpf(den);
    }

    #pragma unroll
    for (int d = 32; d >= 1; d >>= 1)
        lsum += __shfl_down(lsum, d, 64);
    if (lane == 0) {
        const int slot = (blockIdx.z * 256 + blockIdx.y * 16 + blockIdx.x) & (NSLOT - 1);
        atomicAdd(&acc[slot], (double)lsum);
    }
}

__global__ void ssim_final(const double* __restrict__ acc, float* __restrict__ out) {
    const int l = threadIdx.x;   // 64 threads
    double s = acc[l] + acc[l + 64] + acc[l + 128] + acc[l + 192];
    #pragma unroll
    for (int d = 32; d >= 1; d >>= 1)
        s += __shfl_down(s, d, 64);
    if (l == 0)
        out[0] = 1.0f - (float)(s / (double)((size_t)NP * IMG * IMG));
}

extern "C" void kernel_launch(void* const* d_in, const int* in_sizes, int n_in,
                              void* d_out, int out_size, void* d_ws, size_t ws_size,
                              hipStream_t stream) {
    const float* img1 = (const float*)d_in[0];
    const float* img2 = (const float*)d_in[1];
    float* out = (float*)d_out;
    double* acc = (double*)d_ws;
    ushort* gw = (ushort*)((char*)d_ws + NSLOT * sizeof(double));

    hipMemsetAsync(d_ws, 0, NSLOT * sizeof(double), stream);
    build_g<<<1, 64, 0, stream>>>(gw);

    dim3 grid(IMG / TW, IMG / TH, NP);
    ssim_main<<<grid, dim3(64), 0, stream>>>(img1, img2, gw, acc);
    ssim_final<<<1, dim3(64), 0, stream>>>(acc, out);
}